// Round 12
// baseline (3348.163 us; speedup 1.0000x reference)
//
#include <hip/hip_runtime.h>
#include <hip/hip_bf16.h>

#define SEQ 512
#define BATCH 64
#define HID 1024

typedef __bf16 bf16x8 __attribute__((ext_vector_type(8)));
typedef __bf16 bf16x4 __attribute__((ext_vector_type(4)));
typedef float f32x4 __attribute__((ext_vector_type(4)));
typedef unsigned uint32x2 __attribute__((ext_vector_type(2)));

__device__ __forceinline__ float sigm(float x) { return 1.0f / (1.0f + __expf(-x)); }
__device__ __forceinline__ float tanh_(float x) { return 2.0f / (1.0f + __expf(-2.0f * x)) - 1.0f; }

// device-coherent (LLC coherence point) helpers — sc0 sc1 only (sc0-alone
// refuted for cross-CU coherence on gfx950, round 10).
__device__ __forceinline__ void cload_b128(bf16x8* d, const __bf16* p) {
    asm volatile("global_load_dwordx4 %0, %1, off sc0 sc1" : "=v"(*d) : "v"(p));
}
__device__ __forceinline__ void cstore_b64(__bf16* p, bf16x4 v) {
    uint32x2 uv = __builtin_bit_cast(uint32x2, v);
    asm volatile("global_store_dwordx2 %0, %1, off sc0 sc1" :: "v"(p), "v"(uv));
}
__device__ __forceinline__ void cstore_b32(unsigned* p, unsigned v) {
    asm volatile("global_store_dword %0, %1, off sc0 sc1" :: "v"(p), "v"(v));
}
__device__ __forceinline__ unsigned cload_b32(const unsigned* p) {
    unsigned r;
    asm volatile("global_load_dword %0, %1, off sc0 sc1\n\ts_waitcnt vmcnt(0)"
                 : "=v"(r) : "v"(p) : "memory");
    __builtin_amdgcn_sched_barrier(0);
    return r;
}
__device__ __forceinline__ void vmcnt0() {
    asm volatile("s_waitcnt vmcnt(0)" ::: "memory");
    __builtin_amdgcn_sched_barrier(0);
}

// ---------------------------------------------------------------------------
// f32 -> bf16 conversion (n multiple of 4)
// ---------------------------------------------------------------------------
__global__ __launch_bounds__(256) void cvt_f32_bf16(const float* __restrict__ src,
                                                     __bf16* __restrict__ dst, int n)
{
    int i = (blockIdx.x * 256 + threadIdx.x) * 4;
    if (i < n) {
        f32x4 v = *(const f32x4*)(src + i);
        bf16x4 o;
        #pragma unroll
        for (int j = 0; j < 4; ++j) o[j] = (__bf16)v[j];
        *(bf16x4*)(dst + i) = o;
    }
}

// ---------------------------------------------------------------------------
// G layout (tile-blocked): E(t,rg,j,gate,r8,c16) =
//   (((t*8+rg)*64 + j)*3 + gate)*128 + r8*16 + c16   (768B per (t,rg,j) block)
// ---------------------------------------------------------------------------

// ---------------------------------------------------------------------------
// Phase A v2 (m97 pattern), unchanged from round 8 (proven).
// ---------------------------------------------------------------------------
__global__ __launch_bounds__(256) void gru_phaseA2(
    const __bf16* __restrict__ xb,
    const __bf16* __restrict__ Wrb, const __bf16* __restrict__ Wub,
    const __bf16* __restrict__ Wxb,
    const float* __restrict__ br, const float* __restrict__ bu,
    const float* __restrict__ bx, __bf16* __restrict__ G)
{
    __shared__ __bf16 Al[128 * 64];
    __shared__ __bf16 Bl[128 * 64];

    const int NT = 24;
    int mt = blockIdx.x / NT, nt = blockIdx.x % NT;
    int m0 = mt * 128, n0 = nt * 128;

    const __bf16* W; const float* bias; int wstride, nb, gate;
    if (n0 < HID)          { W = Wrb; bias = br; wstride = 2 * HID; nb = n0;           gate = 0; }
    else if (n0 < 2 * HID) { W = Wub; bias = bu; wstride = 2 * HID; nb = n0 - HID;     gate = 1; }
    else                   { W = Wxb; bias = bx; wstride = HID;     nb = n0 - 2 * HID; gate = 2; }

    const int tid = threadIdx.x;
    const int lane = tid & 63, w = tid >> 6;
    const int llo = lane & 15, lhi = lane >> 4;
    const int wm = (w & 1) * 64, wn = (w >> 1) * 64;

    f32x4 acc[4][4] = {};

    for (int k0 = 0; k0 < HID; k0 += 64) {
        __syncthreads();
        #pragma unroll
        for (int s = 0; s < 4; ++s) {
            int idx = s * 256 + tid;
            int r = idx >> 3, c16 = idx & 7;
            int eoff = (c16 * 8) ^ ((r & 7) << 3);
            const __bf16* ga = xb + (size_t)(m0 + r) * HID + k0 + eoff;
            char* la = (char*)Al + (size_t)(s * 256 + w * 64) * 16;
            __builtin_amdgcn_global_load_lds(
                (const __attribute__((address_space(1))) void*)ga,
                (__attribute__((address_space(3))) void*)la, 16, 0, 0);
        }
        #pragma unroll
        for (int s = 0; s < 4; ++s) {
            int idx = s * 256 + tid;
            int r = idx >> 3, c16 = idx & 7;
            int eoff = (c16 * 8) ^ ((r & 7) << 3);
            const __bf16* gb = W + (size_t)(nb + r) * wstride + k0 + eoff;
            char* lb = (char*)Bl + (size_t)(s * 256 + w * 64) * 16;
            __builtin_amdgcn_global_load_lds(
                (const __attribute__((address_space(1))) void*)gb,
                (__attribute__((address_space(3))) void*)lb, 16, 0, 0);
        }
        __syncthreads();

        #pragma unroll
        for (int kk = 0; kk < 2; ++kk) {
            bf16x8 a[4], b[4];
            #pragma unroll
            for (int mi = 0; mi < 4; ++mi) {
                int row = wm + mi * 16 + llo;
                a[mi] = *(const bf16x8*)((const char*)Al + row * 128
                          + ((kk * 64 + lhi * 16) ^ ((row & 7) << 4)));
            }
            #pragma unroll
            for (int ni = 0; ni < 4; ++ni) {
                int row = wn + ni * 16 + llo;
                b[ni] = *(const bf16x8*)((const char*)Bl + row * 128
                          + ((kk * 64 + lhi * 16) ^ ((row & 7) << 4)));
            }
            #pragma unroll
            for (int mi = 0; mi < 4; ++mi)
                #pragma unroll
                for (int ni = 0; ni < 4; ++ni)
                    acc[mi][ni] = __builtin_amdgcn_mfma_f32_16x16x32_bf16(a[mi], b[ni], acc[mi][ni], 0, 0, 0);
        }
    }

    #pragma unroll
    for (int ni = 0; ni < 4; ++ni) {
        int cg0 = nb + wn + ni * 16;
        int jn = cg0 >> 4;
        float bv = bias[cg0 + llo];
        #pragma unroll
        for (int mi = 0; mi < 4; ++mi) {
            #pragma unroll
            for (int i = 0; i < 4; ++i) {
                int m = m0 + wm + mi * 16 + lhi * 4 + i;
                int tt = m >> 6, b = m & 63;
                size_t addr = ((((size_t)tt * 8 + (b >> 3)) * 64 + jn) * 3 + gate) * 128
                            + (b & 7) * 16 + llo;
                G[addr] = (__bf16)(acc[mi][ni][i] + bv);
            }
        }
    }
}

// ---------------------------------------------------------------------------
// Phase A fallback (f32 x on the fly), tile-blocked G epilogue.
// ---------------------------------------------------------------------------
__global__ __launch_bounds__(256) void gru_phaseA_f32(
    const float* __restrict__ xf,
    const __bf16* __restrict__ Wrb, const __bf16* __restrict__ Wub,
    const __bf16* __restrict__ Wxb,
    const float* __restrict__ br, const float* __restrict__ bu,
    const float* __restrict__ bx, __bf16* __restrict__ G)
{
    const int NT = (3 * HID) / 64;
    int mt = blockIdx.x / NT;
    int nt = blockIdx.x % NT;
    int m0 = mt * 128, n0 = nt * 64;

    const __bf16* W; const float* bias; int wstride, nb, gate;
    if (n0 < HID)          { W = Wrb; bias = br; wstride = 2 * HID; nb = n0;           gate = 0; }
    else if (n0 < 2 * HID) { W = Wub; bias = bu; wstride = 2 * HID; nb = n0 - HID;     gate = 1; }
    else                   { W = Wxb; bias = bx; wstride = HID;     nb = n0 - 2 * HID; gate = 2; }

    int lane = threadIdx.x & 63, w = threadIdx.x >> 6;
    int llo = lane & 15, lhi = lane >> 4;
    int wm = (w & 1) * 64, wn = (w >> 1) * 32;

    f32x4 acc[4][2] = {};
    #pragma unroll 2
    for (int k0 = 0; k0 < HID; k0 += 32) {
        int ka = k0 + lhi * 8;
        bf16x8 af[4], bfr[2];
        #pragma unroll
        for (int mi = 0; mi < 4; ++mi) {
            size_t roff = (size_t)(m0 + wm + mi * 16 + llo) * HID + ka;
            f32x4 lo = *(const f32x4*)(xf + roff);
            f32x4 hi = *(const f32x4*)(xf + roff + 4);
            #pragma unroll
            for (int jj = 0; jj < 4; ++jj) { af[mi][jj] = (__bf16)lo[jj]; af[mi][4 + jj] = (__bf16)hi[jj]; }
        }
        #pragma unroll
        for (int ni = 0; ni < 2; ++ni)
            bfr[ni] = *(const bf16x8*)(W + (size_t)(nb + wn + ni * 16 + llo) * wstride + ka);
        #pragma unroll
        for (int mi = 0; mi < 4; ++mi)
            #pragma unroll
            for (int ni = 0; ni < 2; ++ni)
                acc[mi][ni] = __builtin_amdgcn_mfma_f32_16x16x32_bf16(af[mi], bfr[ni], acc[mi][ni], 0, 0, 0);
    }
    #pragma unroll
    for (int ni = 0; ni < 2; ++ni) {
        int cg0 = nb + wn + ni * 16;
        int jn = cg0 >> 4;
        float bv = bias[cg0 + llo];
        #pragma unroll
        for (int mi = 0; mi < 4; ++mi) {
            #pragma unroll
            for (int i = 0; i < 4; ++i) {
                int m = m0 + wm + mi * 16 + lhi * 4 + i;
                int tt = m >> 6, b = m & 63;
                size_t addr = ((((size_t)tt * 8 + (b >> 3)) * 64 + jn) * 3 + gate) * 128
                            + (b & 7) * 16 + llo;
                G[addr] = (__bf16)(acc[mi][ni][i] + bv);
            }
        }
    }
}

// ---------------------------------------------------------------------------
// Init: hg parity0 = bf16(prev); zero the 2048 per-WAVE flag lines (128B).
// ---------------------------------------------------------------------------
__global__ __launch_bounds__(256) void gru_init(const float* __restrict__ prev,
                                                __bf16* __restrict__ hg,
                                                unsigned* __restrict__ flags)
{
    int i = blockIdx.x * 256 + threadIdx.x;
    if (i < 2048 * 32) flags[i] = 0u;
    if (i < BATCH * HID) hg[i] = (__bf16)prev[i];
}

// ---------------------------------------------------------------------------
// Phase B v11 = R8 (proven best, 2002us) + three surgical cuts:
//  1. PER-WAVE private flag lines (2048 x 128B): each wave drains only its
//     own 2 rows (vmcnt0) then stores its own flag -> bar2 deleted, publishes
//     parallel. Poll = 64 private lines (v5-proven); no shared store lines
//     (v8 lesson).
//  2. b64 transposed epilogue (R7-proven): 8 lanes/wave store one 8B segment
//     (row, 4 cols) each -> 4x fewer store messages in the drain.
//  3. Register G prefetch (v10-proven) replaces global_load_lds Gld.
// WAR safety (R8 argument, unchanged): the WG's four waves' polls jointly
// cover all 64 producer WGs of the chain; flag(t) from any wave of WG R
// implies R passed bar1(t-1), i.e. finished reading h_{t-1}; h_{t+1}
// (same parity as h_{t-1}) is written only post-bar1(t), after all 4 polls.
// ---------------------------------------------------------------------------
__global__ __launch_bounds__(256, 2) void gru_phaseB(
    const __bf16* __restrict__ Wrb, const __bf16* __restrict__ Wub,
    const __bf16* __restrict__ Wob, const float* __restrict__ bo,
    const float* __restrict__ prev, const __bf16* __restrict__ G,
    __bf16* __restrict__ hg, unsigned* __restrict__ flags,
    float* __restrict__ out)
{
    __shared__ float gbuf[2][3][4][128];   // [parity][gate][ks][r8*16+c16] 12KB

    const int gwg = blockIdx.x;
    const int j = gwg & 63, rg = gwg >> 6;
    const int tid = threadIdx.x;
    const int lane = tid & 63, ks = tid >> 6;
    const int llo = lane & 15, lhi = lane >> 4;

    // ---- this wave's K-quarter of all 3 gate weight sets (96 VGPRs) ----
    bf16x8 wV[3][8];
    {
        const __bf16* w0 = Wrb + (size_t)(16 * j + llo) * (2 * HID) + HID + ks * 256 + lhi * 8;
        const __bf16* w1 = Wub + (size_t)(16 * j + llo) * (2 * HID) + HID + ks * 256 + lhi * 8;
        const __bf16* w2 = Wob + (size_t)(16 * j + llo) * HID + ks * 256 + lhi * 8;
        #pragma unroll
        for (int kk = 0; kk < 8; ++kk) {
            wV[0][kk] = *(const bf16x8*)(w0 + kk * 32);
            wV[1][kk] = *(const bf16x8*)(w1 + kk * 32);
            wV[2][kk] = *(const bf16x8*)(w2 + kk * 32);
        }
    }

    // ---- epilogue state: lanes<8 per wave; lane -> (row=2ks+(lane>>2), 4 cols) ----
    const int erow = 2 * ks + (lane >> 2);
    const int ecb = (lane & 3) * 4;          // col base within the 16
    const bool elane = lane < 8;
    f32x4 hf = {}, bov = {};
    bf16x4 grb = {}, gub = {}, gxb = {};
    if (elane) {
        hf  = *(const f32x4*)(prev + (size_t)(8 * rg + erow) * HID + 16 * j + ecb);
        bov = *(const f32x4*)(bo + 16 * j + ecb);
        const __bf16* Gb = G + (((size_t)0 * 8 + rg) * 64 + j) * 384;
        int idx = erow * 16 + ecb;
        grb = *(const bf16x4*)(Gb + idx);
        gub = *(const bf16x4*)(Gb + 128 + idx);
        gxb = *(const bf16x4*)(Gb + 256 + idx);
    }

    // per-wave private flag lines
    unsigned* fstore = flags + (size_t)(gwg * 4 + ks) * 32;
    const unsigned* fpoll = flags
        + (size_t)(((rg * 64 + 16 * ks + (lane >> 2)) * 4) + (lane & 3)) * 32;

    const int hrow = 8 * rg + (llo & 7);

    f32x4 ob[8];
    for (int t0 = 0; t0 < SEQ; t0 += 8) {
        #pragma unroll
        for (int s = 0; s < 8; ++s) {
            const int t = t0 + s;
            const int p = t & 1;
            // ---- poll: all 64 producer-waves of my K-quarter (private lines) ----
            if (t > 0) {
                int guard = 0;
                for (;;) {
                    unsigned v = cload_b32(fpoll);
                    if (__all((int)(v >= (unsigned)t))) break;
                    if (++guard >= (1 << 20)) break;
                }
            }
            // ---- load h K-quarter (rows duplicated llo&7), 8 x b128 coherent ----
            const __bf16* hk = hg + (size_t)p * (BATCH * HID)
                             + (size_t)hrow * HID + ks * 256 + lhi * 8;
            bf16x8 hv[8];
            #pragma unroll
            for (int kk = 0; kk < 8; ++kk) cload_b128(&hv[kk], hk + kk * 32);
            vmcnt0();
            // ---- 24 MFMA: 3 gates x 8 K-blocks ----
            f32x4 aR = {}, aU = {}, aO = {};
            #pragma unroll
            for (int kk = 0; kk < 8; ++kk) {
                aR = __builtin_amdgcn_mfma_f32_16x16x32_bf16(hv[kk], wV[0][kk], aR, 0, 0, 0);
                aU = __builtin_amdgcn_mfma_f32_16x16x32_bf16(hv[kk], wV[1][kk], aU, 0, 0, 0);
                aO = __builtin_amdgcn_mfma_f32_16x16x32_bf16(hv[kk], wV[2][kk], aO, 0, 0, 0);
            }
            // ---- partials to gbuf (unique rows 0..7 only) ----
            if (lhi < 2) {
                #pragma unroll
                for (int i = 0; i < 4; ++i) {
                    gbuf[p][0][ks][(lhi * 4 + i) * 16 + llo] = aR[i];
                    gbuf[p][1][ks][(lhi * 4 + i) * 16 + llo] = aU[i];
                    gbuf[p][2][ks][(lhi * 4 + i) * 16 + llo] = aO[i];
                }
            }
            __syncthreads();   // bar1: gbuf ready; WAR anchor (post-poll of all waves)

            // ---- per-wave epilogue: 8 lanes, one (row, 4 cols) each ----
            f32x4 hnew = {};
            if (elane) {
                int idx = erow * 16 + ecb;
                f32x4 sR = *(const f32x4*)&gbuf[p][0][0][idx];
                f32x4 sU = *(const f32x4*)&gbuf[p][1][0][idx];
                f32x4 sO = *(const f32x4*)&gbuf[p][2][0][idx];
                #pragma unroll
                for (int kk = 1; kk < 4; ++kk) {
                    sR += *(const f32x4*)&gbuf[p][0][kk][idx];
                    sU += *(const f32x4*)&gbuf[p][1][kk][idx];
                    sO += *(const f32x4*)&gbuf[p][2][kk][idx];
                }
                bf16x4 hb;
                #pragma unroll
                for (int i = 0; i < 4; ++i) {
                    float r = sigm(sR[i] + (float)grb[i]);
                    float u = sigm(sU[i] + (float)gub[i]);
                    float c = tanh_((sO[i] + bov[i]) * r + (float)gxb[i]);
                    float hn = (1.0f - u) * c + u * hf[i];
                    hf[i] = hn; hnew[i] = hn; hb[i] = (__bf16)hn;
                }
                cstore_b64(hg + (size_t)((t + 1) & 1) * (BATCH * HID)
                              + (size_t)(8 * rg + erow) * HID + 16 * j + ecb, hb);
            }
            vmcnt0();          // this wave's h stores at coherence point
            if (lane == 0) cstore_b32(fstore, (unsigned)(t + 1));
            // ---- deferred: register G prefetch for t+1 (off the sync chain) ----
            if (elane && t + 1 < SEQ) {
                const __bf16* Gb = G + (((size_t)(t + 1) * 8 + rg) * 64 + j) * 384;
                int idx = erow * 16 + ecb;
                grb = *(const bf16x4*)(Gb + idx);
                gub = *(const bf16x4*)(Gb + 128 + idx);
                gxb = *(const bf16x4*)(Gb + 256 + idx);
            }
            ob[s] = hnew;
        }
        // ---- batched out flush (8 steps, f32x4 per lane) ----
        if (elane) {
            #pragma unroll
            for (int s = 0; s < 8; ++s)
                __builtin_nontemporal_store(ob[s],
                    (f32x4*)(out + ((size_t)(t0 + s) * BATCH + 8 * rg + erow) * HID + 16 * j + ecb));
            if (t0 + 8 == SEQ)
                __builtin_nontemporal_store(ob[7],
                    (f32x4*)(out + ((size_t)SEQ * BATCH + 8 * rg + erow) * HID + 16 * j + ecb));
        }
    }
}

extern "C" void kernel_launch(void* const* d_in, const int* in_sizes, int n_in,
                              void* d_out, int out_size, void* d_ws, size_t ws_size,
                              hipStream_t stream) {
    (void)in_sizes; (void)n_in; (void)out_size;
    const float* x    = (const float*)d_in[0];
    const float* prev = (const float*)d_in[1];
    const float* Wr   = (const float*)d_in[2];
    const float* br   = (const float*)d_in[3];
    const float* Wu   = (const float*)d_in[4];
    const float* bu   = (const float*)d_in[5];
    const float* Wo   = (const float*)d_in[6];
    const float* bo   = (const float*)d_in[7];
    const float* Wx   = (const float*)d_in[8];
    const float* bx   = (const float*)d_in[9];
    float* out = (float*)d_out;

    // workspace layout (bytes)
    const size_t G_ELEMS  = (size_t)SEQ * BATCH * 3 * HID;
    const size_t WR_ELEMS = (size_t)HID * 2 * HID;
    const size_t WO_ELEMS = (size_t)HID * HID;
    char* ws = (char*)d_ws;
    size_t off = 0;
    __bf16* G   = (__bf16*)(ws + off); off += G_ELEMS * 2;
    __bf16* Wrb = (__bf16*)(ws + off); off += WR_ELEMS * 2;
    __bf16* Wub = (__bf16*)(ws + off); off += WR_ELEMS * 2;
    __bf16* Wob = (__bf16*)(ws + off); off += WO_ELEMS * 2;
    __bf16* Wxb = (__bf16*)(ws + off); off += WO_ELEMS * 2;
    __bf16* hg  = (__bf16*)(ws + off); off += (size_t)2 * BATCH * HID * 2;
    unsigned* flags = (unsigned*)(ws + off); off += 2048 * 32 * 4;   // 256KB per-wave lines
    const size_t X_ELEMS = (size_t)SEQ * BATCH * HID;
    bool use_xb = (ws_size >= off + X_ELEMS * 2);
    __bf16* xb = (__bf16*)(ws + off);

    cvt_f32_bf16<<<(int)(WR_ELEMS / 4 / 256), 256, 0, stream>>>(Wr, Wrb, (int)WR_ELEMS);
    cvt_f32_bf16<<<(int)(WR_ELEMS / 4 / 256), 256, 0, stream>>>(Wu, Wub, (int)WR_ELEMS);
    cvt_f32_bf16<<<(int)(WO_ELEMS / 4 / 256), 256, 0, stream>>>(Wo, Wob, (int)WO_ELEMS);
    cvt_f32_bf16<<<(int)(WO_ELEMS / 4 / 256), 256, 0, stream>>>(Wx, Wxb, (int)WO_ELEMS);
    if (use_xb)
        cvt_f32_bf16<<<(int)(X_ELEMS / 4 / 256), 256, 0, stream>>>(x, xb, (int)X_ELEMS);

    gru_init<<<(BATCH * HID) / 256, 256, 0, stream>>>(prev, hg, flags);

    if (use_xb) {
        gru_phaseA2<<<256 * 24, 256, 0, stream>>>(xb, Wrb, Wub, Wxb, br, bu, bx, G);
    } else {
        int gridA = (SEQ * BATCH / 128) * ((3 * HID) / 64);
        gru_phaseA_f32<<<gridA, 256, 0, stream>>>(x, Wrb, Wub, Wxb, br, bu, bx, G);
    }

    gru_phaseB<<<512, 256, 0, stream>>>(Wrb, Wub, Wob, bo, prev, G, hg, flags, out);
}

// Round 13
// 2256.981 us; speedup vs baseline: 1.4835x; 1.4835x over previous
//
#include <hip/hip_runtime.h>
#include <hip/hip_bf16.h>

#define SEQ 512
#define BATCH 64
#define HID 1024

typedef __bf16 bf16x8 __attribute__((ext_vector_type(8)));
typedef __bf16 bf16x4 __attribute__((ext_vector_type(4)));
typedef float f32x4 __attribute__((ext_vector_type(4)));

__device__ __forceinline__ float sigm(float x) { return 1.0f / (1.0f + __expf(-x)); }
__device__ __forceinline__ float tanh_(float x) { return 2.0f / (1.0f + __expf(-2.0f * x)) - 1.0f; }

// device-coherent (LLC coherence point) helpers
__device__ __forceinline__ void cload_b128(bf16x8* d, const __bf16* p) {
    asm volatile("global_load_dwordx4 %0, %1, off sc0 sc1" : "=v"(*d) : "v"(p));
}
__device__ __forceinline__ void cstore_b16(__bf16* p, __bf16 v) {
    unsigned short uv = __builtin_bit_cast(unsigned short, v);
    asm volatile("global_store_short %0, %1, off sc0 sc1" :: "v"(p), "v"(uv));
}
__device__ __forceinline__ void cstore_b32(unsigned* p, unsigned v) {
    asm volatile("global_store_dword %0, %1, off sc0 sc1" :: "v"(p), "v"(v));
}
__device__ __forceinline__ unsigned cload_b32(const unsigned* p) {
    unsigned r;
    asm volatile("global_load_dword %0, %1, off sc0 sc1\n\ts_waitcnt vmcnt(0)"
                 : "=v"(r) : "v"(p) : "memory");
    __builtin_amdgcn_sched_barrier(0);
    return r;
}
__device__ __forceinline__ void vmcnt0() {
    asm volatile("s_waitcnt vmcnt(0)" ::: "memory");
    __builtin_amdgcn_sched_barrier(0);
}

// ---------------------------------------------------------------------------
// f32 -> bf16 conversion (n multiple of 4)
// ---------------------------------------------------------------------------
__global__ __launch_bounds__(256) void cvt_f32_bf16(const float* __restrict__ src,
                                                     __bf16* __restrict__ dst, int n)
{
    int i = (blockIdx.x * 256 + threadIdx.x) * 4;
    if (i < n) {
        f32x4 v = *(const f32x4*)(src + i);
        bf16x4 o;
        #pragma unroll
        for (int j = 0; j < 4; ++j) o[j] = (__bf16)v[j];
        *(bf16x4*)(dst + i) = o;
    }
}

// ---------------------------------------------------------------------------
// G layout (tile-blocked for phaseB): element index
//   E(t, rg, j, gate, r8, c16) = (((t*8+rg)*64 + j)*3 + gate)*128 + r8*16 + c16
// where b = rg*8 + r8 (batch row), col = j*16 + c16 (col within gate).
// Each (t,rg,j) block is 768B contiguous -> phaseB reads it with one
// 48-lane global_load_lds, zero overfetch.
// ---------------------------------------------------------------------------

// ---------------------------------------------------------------------------
// Phase A v2 (m97 pattern): 128x128 tile, BK=64, global_load_lds w16,
// both-sides XOR swizzle; epilogue writes tile-blocked G.
// ---------------------------------------------------------------------------
__global__ __launch_bounds__(256) void gru_phaseA2(
    const __bf16* __restrict__ xb,
    const __bf16* __restrict__ Wrb, const __bf16* __restrict__ Wub,
    const __bf16* __restrict__ Wxb,
    const float* __restrict__ br, const float* __restrict__ bu,
    const float* __restrict__ bx, __bf16* __restrict__ G)
{
    __shared__ __bf16 Al[128 * 64];
    __shared__ __bf16 Bl[128 * 64];

    const int NT = 24;
    int mt = blockIdx.x / NT, nt = blockIdx.x % NT;
    int m0 = mt * 128, n0 = nt * 128;

    const __bf16* W; const float* bias; int wstride, nb, gate;
    if (n0 < HID)          { W = Wrb; bias = br; wstride = 2 * HID; nb = n0;           gate = 0; }
    else if (n0 < 2 * HID) { W = Wub; bias = bu; wstride = 2 * HID; nb = n0 - HID;     gate = 1; }
    else                   { W = Wxb; bias = bx; wstride = HID;     nb = n0 - 2 * HID; gate = 2; }

    const int tid = threadIdx.x;
    const int lane = tid & 63, w = tid >> 6;
    const int llo = lane & 15, lhi = lane >> 4;
    const int wm = (w & 1) * 64, wn = (w >> 1) * 64;

    f32x4 acc[4][4] = {};

    for (int k0 = 0; k0 < HID; k0 += 64) {
        __syncthreads();
        #pragma unroll
        for (int s = 0; s < 4; ++s) {
            int idx = s * 256 + tid;
            int r = idx >> 3, c16 = idx & 7;
            int eoff = (c16 * 8) ^ ((r & 7) << 3);
            const __bf16* ga = xb + (size_t)(m0 + r) * HID + k0 + eoff;
            char* la = (char*)Al + (size_t)(s * 256 + w * 64) * 16;
            __builtin_amdgcn_global_load_lds(
                (const __attribute__((address_space(1))) void*)ga,
                (__attribute__((address_space(3))) void*)la, 16, 0, 0);
        }
        #pragma unroll
        for (int s = 0; s < 4; ++s) {
            int idx = s * 256 + tid;
            int r = idx >> 3, c16 = idx & 7;
            int eoff = (c16 * 8) ^ ((r & 7) << 3);
            const __bf16* gb = W + (size_t)(nb + r) * wstride + k0 + eoff;
            char* lb = (char*)Bl + (size_t)(s * 256 + w * 64) * 16;
            __builtin_amdgcn_global_load_lds(
                (const __attribute__((address_space(1))) void*)gb,
                (__attribute__((address_space(3))) void*)lb, 16, 0, 0);
        }
        __syncthreads();

        #pragma unroll
        for (int kk = 0; kk < 2; ++kk) {
            bf16x8 a[4], b[4];
            #pragma unroll
            for (int mi = 0; mi < 4; ++mi) {
                int row = wm + mi * 16 + llo;
                a[mi] = *(const bf16x8*)((const char*)Al + row * 128
                          + ((kk * 64 + lhi * 16) ^ ((row & 7) << 4)));
            }
            #pragma unroll
            for (int ni = 0; ni < 4; ++ni) {
                int row = wn + ni * 16 + llo;
                b[ni] = *(const bf16x8*)((const char*)Bl + row * 128
                          + ((kk * 64 + lhi * 16) ^ ((row & 7) << 4)));
            }
            #pragma unroll
            for (int mi = 0; mi < 4; ++mi)
                #pragma unroll
                for (int ni = 0; ni < 4; ++ni)
                    acc[mi][ni] = __builtin_amdgcn_mfma_f32_16x16x32_bf16(a[mi], b[ni], acc[mi][ni], 0, 0, 0);
        }
    }

    #pragma unroll
    for (int ni = 0; ni < 4; ++ni) {
        int cg0 = nb + wn + ni * 16;      // col-in-gate base (multiple of 16)
        int jn = cg0 >> 4;
        float bv = bias[cg0 + llo];
        #pragma unroll
        for (int mi = 0; mi < 4; ++mi) {
            #pragma unroll
            for (int i = 0; i < 4; ++i) {
                int m = m0 + wm + mi * 16 + lhi * 4 + i;
                int tt = m >> 6, b = m & 63;
                size_t addr = ((((size_t)tt * 8 + (b >> 3)) * 64 + jn) * 3 + gate) * 128
                            + (b & 7) * 16 + llo;
                G[addr] = (__bf16)(acc[mi][ni][i] + bv);
            }
        }
    }
}

// ---------------------------------------------------------------------------
// Phase A fallback (f32 x on the fly), tile-blocked G epilogue.
// ---------------------------------------------------------------------------
__global__ __launch_bounds__(256) void gru_phaseA_f32(
    const float* __restrict__ xf,
    const __bf16* __restrict__ Wrb, const __bf16* __restrict__ Wub,
    const __bf16* __restrict__ Wxb,
    const float* __restrict__ br, const float* __restrict__ bu,
    const float* __restrict__ bx, __bf16* __restrict__ G)
{
    const int NT = (3 * HID) / 64;
    int mt = blockIdx.x / NT;
    int nt = blockIdx.x % NT;
    int m0 = mt * 128, n0 = nt * 64;

    const __bf16* W; const float* bias; int wstride, nb, gate;
    if (n0 < HID)          { W = Wrb; bias = br; wstride = 2 * HID; nb = n0;           gate = 0; }
    else if (n0 < 2 * HID) { W = Wub; bias = bu; wstride = 2 * HID; nb = n0 - HID;     gate = 1; }
    else                   { W = Wxb; bias = bx; wstride = HID;     nb = n0 - 2 * HID; gate = 2; }

    int lane = threadIdx.x & 63, w = threadIdx.x >> 6;
    int llo = lane & 15, lhi = lane >> 4;
    int wm = (w & 1) * 64, wn = (w >> 1) * 32;

    f32x4 acc[4][2] = {};
    #pragma unroll 2
    for (int k0 = 0; k0 < HID; k0 += 32) {
        int ka = k0 + lhi * 8;
        bf16x8 af[4], bfr[2];
        #pragma unroll
        for (int mi = 0; mi < 4; ++mi) {
            size_t roff = (size_t)(m0 + wm + mi * 16 + llo) * HID + ka;
            f32x4 lo = *(const f32x4*)(xf + roff);
            f32x4 hi = *(const f32x4*)(xf + roff + 4);
            #pragma unroll
            for (int jj = 0; jj < 4; ++jj) { af[mi][jj] = (__bf16)lo[jj]; af[mi][4 + jj] = (__bf16)hi[jj]; }
        }
        #pragma unroll
        for (int ni = 0; ni < 2; ++ni)
            bfr[ni] = *(const bf16x8*)(W + (size_t)(nb + wn + ni * 16 + llo) * wstride + ka);
        #pragma unroll
        for (int mi = 0; mi < 4; ++mi)
            #pragma unroll
            for (int ni = 0; ni < 2; ++ni)
                acc[mi][ni] = __builtin_amdgcn_mfma_f32_16x16x32_bf16(af[mi], bfr[ni], acc[mi][ni], 0, 0, 0);
    }
    #pragma unroll
    for (int ni = 0; ni < 2; ++ni) {
        int cg0 = nb + wn + ni * 16;
        int jn = cg0 >> 4;
        float bv = bias[cg0 + llo];
        #pragma unroll
        for (int mi = 0; mi < 4; ++mi) {
            #pragma unroll
            for (int i = 0; i < 4; ++i) {
                int m = m0 + wm + mi * 16 + lhi * 4 + i;
                int tt = m >> 6, b = m & 63;
                size_t addr = ((((size_t)tt * 8 + (b >> 3)) * 64 + jn) * 3 + gate) * 128
                            + (b & 7) * 16 + llo;
                G[addr] = (__bf16)(acc[mi][ni][i] + bv);
            }
        }
    }
}

// ---------------------------------------------------------------------------
// Init: hg parity0 = bf16(prev); zero the 512 per-WG flags (128B-strided).
// ---------------------------------------------------------------------------
__global__ __launch_bounds__(256) void gru_init(const float* __restrict__ prev,
                                                __bf16* __restrict__ hg,
                                                unsigned* __restrict__ flags)
{
    int i = blockIdx.x * 256 + threadIdx.x;
    if (i < 512 * 32) flags[i] = 0u;
    if (i < BATCH * HID) hg[i] = (__bf16)prev[i];
}

// ---------------------------------------------------------------------------
// Phase B v7 (PROVEN BEST — round 8: phaseB 2002us, total 2273us):
// 512 WGs x 4 waves -> 2 WGs/CU, 2 waves/SIMD from DIFFERENT recurrent
// chains (8 independent chains of 8 batch rows each).
// WG (rg,j): 8 rows x 16 cols. Wave ks = K-quarter; all-3-gate weights for
// (16 cols x 256 K) in 96 VGPRs. MFMA A-frag duplicates rows (llo&7).
// Sync: per-WG flag on own 128B line, plain coherent store; consumer polls
// the 16 producer lines of its K-quarter in ONE load per lane. (Ledger:
// private stores + 16-line poll beat atomics, dense flags, per-wave flags,
// and inline-tagged h across rounds 6-12.)
// Epilogue parallel across all 4 waves (1 value/lane, lanes<32), h-store
// drain via syncthreads, then single flag store. G prefetched per step as
// one contiguous 768B block via global_load_lds (zero overfetch).
// ---------------------------------------------------------------------------
__global__ __launch_bounds__(256, 2) void gru_phaseB(
    const __bf16* __restrict__ Wrb, const __bf16* __restrict__ Wub,
    const __bf16* __restrict__ Wob, const float* __restrict__ bo,
    const float* __restrict__ prev, const __bf16* __restrict__ G,
    __bf16* __restrict__ hg, unsigned* __restrict__ flags,
    float* __restrict__ out)
{
    __shared__ float gbuf[2][3][4][128];   // [parity][gate][ks][r8*16+c16] 12KB
    __shared__ __bf16 Gld[2][384];         // [parity][gate*128 + r8*16+c16] 1.5KB

    const int gwg = blockIdx.x;
    const int j = gwg & 63, rg = gwg >> 6;
    const int tid = threadIdx.x;
    const int lane = tid & 63, ks = tid >> 6;
    const int llo = lane & 15, lhi = lane >> 4;

    // ---- stage this wave's K-quarter of all 3 gate weight sets into VGPRs ----
    bf16x8 wV[3][8];
    {
        const __bf16* w0 = Wrb + (size_t)(16 * j + llo) * (2 * HID) + HID + ks * 256 + lhi * 8;
        const __bf16* w1 = Wub + (size_t)(16 * j + llo) * (2 * HID) + HID + ks * 256 + lhi * 8;
        const __bf16* w2 = Wob + (size_t)(16 * j + llo) * HID + ks * 256 + lhi * 8;
        #pragma unroll
        for (int kk = 0; kk < 8; ++kk) {
            wV[0][kk] = *(const bf16x8*)(w0 + kk * 32);
            wV[1][kk] = *(const bf16x8*)(w1 + kk * 32);
            wV[2][kk] = *(const bf16x8*)(w2 + kk * 32);
        }
    }

    // ---- epilogue lane state: wave ks owns rows {2ks, 2ks+1}; lanes<32 ----
    const int erow = 2 * ks + ((lane >> 4) & 1);
    const int ecol = lane & 15;
    float hf = 0.f, bov = 0.f;
    if (lane < 32) {
        hf = prev[(size_t)(8 * rg + erow) * HID + 16 * j + ecol];
        bov = bo[16 * j + ecol];
    }

    // ---- prologue: prefetch G block for t=0 ----
    if (ks == 0 && lane < 48) {
        const __bf16* gsrc = G + (((size_t)0 * 8 + rg) * 64 + j) * 384 + lane * 8;
        __builtin_amdgcn_global_load_lds(
            (const __attribute__((address_space(1))) void*)gsrc,
            (__attribute__((address_space(3))) void*)((char*)&Gld[0][0] + lane * 16),
            16, 0, 0);
    }

    for (int t = 0; t < SEQ; ++t) {
        const int p = t & 1;
        // ---- poll: the 16 producers of my K-quarter must have published h_t ----
        if (t > 0) {
            const unsigned* fp = flags + (size_t)(rg * 64 + 16 * ks + llo) * 32;
            int guard = 0;
            for (;;) {
                unsigned v = cload_b32(fp);
                if (__all((int)(v >= (unsigned)t))) break;
                if (++guard >= (1 << 20)) break;
            }
        }
        // ---- load h K-quarter (rows duplicated llo&7), 8 x b128 coherent ----
        const __bf16* hk = hg + (size_t)p * (BATCH * HID)
                         + (size_t)(8 * rg + (llo & 7)) * HID + ks * 256 + lhi * 8;
        bf16x8 hv[8];
        #pragma unroll
        for (int kk = 0; kk < 8; ++kk) cload_b128(&hv[kk], hk + kk * 32);
        vmcnt0();
        // ---- 24 MFMA: 3 gates x 8 K-blocks ----
        f32x4 aR = {}, aU = {}, aO = {};
        #pragma unroll
        for (int kk = 0; kk < 8; ++kk) {
            aR = __builtin_amdgcn_mfma_f32_16x16x32_bf16(hv[kk], wV[0][kk], aR, 0, 0, 0);
            aU = __builtin_amdgcn_mfma_f32_16x16x32_bf16(hv[kk], wV[1][kk], aU, 0, 0, 0);
            aO = __builtin_amdgcn_mfma_f32_16x16x32_bf16(hv[kk], wV[2][kk], aO, 0, 0, 0);
        }
        // ---- partials to gbuf (unique rows 0..7 only) ----
        if (lhi < 2) {
            #pragma unroll
            for (int i = 0; i < 4; ++i) {
                gbuf[p][0][ks][(lhi * 4 + i) * 16 + llo] = aR[i];
                gbuf[p][1][ks][(lhi * 4 + i) * 16 + llo] = aU[i];
                gbuf[p][2][ks][(lhi * 4 + i) * 16 + llo] = aO[i];
            }
        }
        __syncthreads();   // bar1: gbuf + Gld[p] ready

        // ---- parallel epilogue: every wave, lanes<32, one (row,col) each ----
        float hnew = 0.f;
        if (lane < 32) {
            int idx = erow * 16 + ecol;
            float sR = gbuf[p][0][0][idx] + gbuf[p][0][1][idx] + gbuf[p][0][2][idx] + gbuf[p][0][3][idx];
            float sU = gbuf[p][1][0][idx] + gbuf[p][1][1][idx] + gbuf[p][1][2][idx] + gbuf[p][1][3][idx];
            float sO = gbuf[p][2][0][idx] + gbuf[p][2][1][idx] + gbuf[p][2][2][idx] + gbuf[p][2][3][idx];
            float gr = (float)Gld[p][0 * 128 + idx];
            float gu = (float)Gld[p][1 * 128 + idx];
            float gx = (float)Gld[p][2 * 128 + idx];
            float r = sigm(sR + gr);
            float u = sigm(sU + gu);
            float c = tanh_((sO + bov) * r + gx);
            hnew = (1.0f - u) * c + u * hf;
            hf = hnew;
            cstore_b16(hg + (size_t)(p ^ 1) * (BATCH * HID)
                          + (size_t)(8 * rg + erow) * HID + 16 * j + ecol, (__bf16)hnew);
        }
        __syncthreads();   // bar2: drains ALL waves' h stores to coherence point
        if (tid == 0)
            cstore_b32(flags + (size_t)(rg * 64 + j) * 32, (unsigned)(t + 1));
        // ---- deferred (overlaps peers' polling): G(t+1) prefetch + out ----
        if (ks == 0 && lane < 48 && t + 1 < SEQ) {
            const __bf16* gsrc = G + (((size_t)(t + 1) * 8 + rg) * 64 + j) * 384 + lane * 8;
            __builtin_amdgcn_global_load_lds(
                (const __attribute__((address_space(1))) void*)gsrc,
                (__attribute__((address_space(3))) void*)((char*)&Gld[p ^ 1][0] + lane * 16),
                16, 0, 0);
        }
        if (lane < 32) {
            __builtin_nontemporal_store(hnew,
                out + ((size_t)t * BATCH + 8 * rg + erow) * HID + 16 * j + ecol);
            if (t == SEQ - 1)
                __builtin_nontemporal_store(hnew,
                    out + ((size_t)SEQ * BATCH + 8 * rg + erow) * HID + 16 * j + ecol);
        }
    }
}

extern "C" void kernel_launch(void* const* d_in, const int* in_sizes, int n_in,
                              void* d_out, int out_size, void* d_ws, size_t ws_size,
                              hipStream_t stream) {
    (void)in_sizes; (void)n_in; (void)out_size;
    const float* x    = (const float*)d_in[0];
    const float* prev = (const float*)d_in[1];
    const float* Wr   = (const float*)d_in[2];
    const float* br   = (const float*)d_in[3];
    const float* Wu   = (const float*)d_in[4];
    const float* bu   = (const float*)d_in[5];
    const float* Wo   = (const float*)d_in[6];
    const float* bo   = (const float*)d_in[7];
    const float* Wx   = (const float*)d_in[8];
    const float* bx   = (const float*)d_in[9];
    float* out = (float*)d_out;

    // workspace layout (bytes)
    const size_t G_ELEMS  = (size_t)SEQ * BATCH * 3 * HID;
    const size_t WR_ELEMS = (size_t)HID * 2 * HID;
    const size_t WO_ELEMS = (size_t)HID * HID;
    char* ws = (char*)d_ws;
    size_t off = 0;
    __bf16* G   = (__bf16*)(ws + off); off += G_ELEMS * 2;
    __bf16* Wrb = (__bf16*)(ws + off); off += WR_ELEMS * 2;
    __bf16* Wub = (__bf16*)(ws + off); off += WR_ELEMS * 2;
    __bf16* Wob = (__bf16*)(ws + off); off += WO_ELEMS * 2;
    __bf16* Wxb = (__bf16*)(ws + off); off += WO_ELEMS * 2;
    __bf16* hg  = (__bf16*)(ws + off); off += (size_t)2 * BATCH * HID * 2;
    unsigned* flags = (unsigned*)(ws + off); off += 512 * 32 * 4;   // 64KB
    const size_t X_ELEMS = (size_t)SEQ * BATCH * HID;
    bool use_xb = (ws_size >= off + X_ELEMS * 2);
    __bf16* xb = (__bf16*)(ws + off);

    cvt_f32_bf16<<<(int)(WR_ELEMS / 4 / 256), 256, 0, stream>>>(Wr, Wrb, (int)WR_ELEMS);
    cvt_f32_bf16<<<(int)(WR_ELEMS / 4 / 256), 256, 0, stream>>>(Wu, Wub, (int)WR_ELEMS);
    cvt_f32_bf16<<<(int)(WO_ELEMS / 4 / 256), 256, 0, stream>>>(Wo, Wob, (int)WO_ELEMS);
    cvt_f32_bf16<<<(int)(WO_ELEMS / 4 / 256), 256, 0, stream>>>(Wx, Wxb, (int)WO_ELEMS);
    if (use_xb)
        cvt_f32_bf16<<<(int)(X_ELEMS / 4 / 256), 256, 0, stream>>>(x, xb, (int)X_ELEMS);

    gru_init<<<(BATCH * HID) / 256, 256, 0, stream>>>(prev, hg, flags);

    if (use_xb) {
        gru_phaseA2<<<256 * 24, 256, 0, stream>>>(xb, Wrb, Wub, Wxb, br, bu, bx, G);
    } else {
        int gridA = (SEQ * BATCH / 128) * ((3 * HID) / 64);
        gru_phaseA_f32<<<gridA, 256, 0, stream>>>(x, Wrb, Wub, Wxb, br, bu, bx, G);
    }

    gru_phaseB<<<512, 256, 0, stream>>>(Wrb, Wub, Wob, bo, prev, G, hg, flags, out);
}